// Round 13
// baseline (26.199 us; speedup 1.0000x reference)
//
#include <hip/hip_runtime.h>
#include <math.h>

#define N_ROWS 8192
#define D 16
#define TILE 128
#define NT 64            /* 8192/128 */
#define NBLK 2080        /* NT*(NT+1)/2 upper-tri tiles = 32*65 */

/* workspace layout (bytes) */
#define OFF_PT   0            /* float  pt[2080] */
#define OFF_PS   16384        /* float  ps[2080] */
#define OFF_AP   32768        /* ushort aP [8192*32] 512KB */
#define OFF_BP   557056       /* ushort bP [8192*32] 512KB */
#define OFF_FOH  1081344      /* ushort foh[8192*8]  128KB */

typedef short  bf16x8 __attribute__((ext_vector_type(8)));
typedef float  f32x4  __attribute__((ext_vector_type(4)));

#define BF_ONE ((unsigned short)0x3F80)

/* codon index -> biosynthetic family id (K resolves to aspartate; '*' -> -1)
   families: 0=glutamate 1=aspartate 2=serine 3=pyruvate 4=aromatic 5=histidine */
__device__ __constant__ signed char FAM_LUT[64] = {
  4,4,3,3, 3,3,3,3,   /* UUU..CUG: F F L L L L L L */
  1,1,1,1, 3,3,3,3,   /* AUU..GUG: I I I M V V V V */
  2,2,2,2, 0,0,0,0,   /* UCU..CCG: S S S S P P P P */
  1,1,1,1, 3,3,3,3,   /* ACU..GCG: T T T T A A A A */
  4,4,-1,-1, 5,5,0,0, /* UAU..CAG: Y Y * * H H Q Q */
  1,1,1,1, 1,1,0,0,   /* AAU..GAG: N N K K D D E E */
  2,2,-1,4, 0,0,0,0,  /* UGU..CGG: C C * W R R R R */
  2,2,0,0, 2,2,2,2    /* AGU..GGG: S S R R G G G G */
};

__device__ __forceinline__ unsigned short f2bf(float f) {   /* RNE, finite inputs */
  unsigned u = __float_as_uint(f);
  u += 0x7fffu + ((u >> 16) & 1u);
  return (unsigned short)(u >> 16);
}
__device__ __forceinline__ float bf2f(unsigned short s) {
  return __uint_as_float((unsigned)s << 16);
}
__device__ __forceinline__ float sqrt_abs(float x) {   /* 1 VALU + 1 trans */
  const float ax = __builtin_fabsf(x);
  float r;
  asm("v_sqrt_f32 %0, %1" : "=v"(r) : "v"(ax));
  return r;
}

/* prep: one thread per row packs the final MFMA operands (ONCE globally).
   Distances are of the bf16-ROUNDED point set; sq computed FROM rounded
   coords (bit-identical to R12's math).
   A : [-2b_bf(0..15) | ONE, ONE, sqi_hi, sqi_lo | 0 x12]
   B : [ b_bf(0..15)  | sqj_hi, sqj_lo, ONE, ONE | 0 x12]
   => acc(A_i, B_j) = sqi + sqj - 2*dot = d2 directly */
__global__ __launch_bounds__(256) void prep_kernel(
    const float* __restrict__ emb, const int* __restrict__ idx,
    unsigned short* __restrict__ aP, unsigned short* __restrict__ bP,
    unsigned short* __restrict__ foh) {
  const int i = blockIdx.x * 256 + threadIdx.x;
  const float4* s4 = (const float4*)(emb + (size_t)i * D);
  float4 a0 = s4[0], a1 = s4[1], a2 = s4[2], a3 = s4[3];
  float v[16];
  v[0]=a0.x; v[1]=a0.y; v[2]=a0.z; v[3]=a0.w;
  v[4]=a1.x; v[5]=a1.y; v[6]=a1.z; v[7]=a1.w;
  v[8]=a2.x; v[9]=a2.y; v[10]=a2.z; v[11]=a2.w;
  v[12]=a3.x; v[13]=a3.y; v[14]=a3.z; v[15]=a3.w;

  unsigned short bh[16];
#pragma unroll
  for (int k = 0; k < 16; ++k) bh[k] = f2bf(v[k]);
  float ss = bf2f(bh[0]) * bf2f(bh[0]);            /* sq of ROUNDED coords */
#pragma unroll
  for (int k = 1; k < 16; ++k) { const float rv = bf2f(bh[k]); ss = fmaf(rv, rv, ss); }
  const unsigned short sqh = f2bf(ss);
  const unsigned short sql = f2bf(ss - bf2f(sqh));

  unsigned short A[32], B[32];
#pragma unroll
  for (int k = 0; k < 16; ++k) {
    A[k] = f2bf(-2.0f * bf2f(bh[k]));   /* exact: == -2 * bh[k] in bf16 */
    B[k] = bh[k];
  }
  A[16] = BF_ONE; A[17] = BF_ONE; A[18] = sqh; A[19] = sql;
  B[16] = sqh;    B[17] = sql;    B[18] = BF_ONE; B[19] = BF_ONE;
#pragma unroll
  for (int k = 20; k < 32; ++k) { A[k] = 0; B[k] = 0; }

#pragma unroll
  for (int c = 0; c < 4; ++c) {
    *(bf16x8*)(aP + (size_t)i * 32 + c * 8) = *(bf16x8*)&A[c * 8];
    *(bf16x8*)(bP + (size_t)i * 32 + c * 8) = *(bf16x8*)&B[c * 8];
  }
  const int f = FAM_LUT[idx[i] & 63];
  unsigned short oh[8];
#pragma unroll
  for (int k = 0; k < 8; ++k) oh[k] = (f == k) ? BF_ONE : (unsigned short)0;
  *(bf16x8*)(foh + (size_t)i * 8) = *(bf16x8*)oh;
}

__global__ __launch_bounds__(512, 4) void pair_kernel(
    const unsigned short* __restrict__ aP, const unsigned short* __restrict__ bP,
    const unsigned short* __restrict__ foh,
    float* __restrict__ pt, float* __restrict__ ps) {
  /* triangular fold: grid (65,32) -> every block a live upper-tri 128x128 tile */
  const int u = blockIdx.y, bx = blockIdx.x;
  int it, jt;
  if (bx < NT - u) { it = u;          jt = u + bx; }
  else             { it = NT - 1 - u; jt = bx - 1; }

  __shared__ __align__(16) unsigned short LB1[4096];  /* 8KB: j-tile B [row][32] */
  __shared__ __align__(16) unsigned short LFB[1024];  /* 2KB: j one-hot */
  __shared__ float rT[8], rS[8];

  const int t  = threadIdx.x;
  const int w  = t >> 6;          /* wave 0..7: i-strip w */
  const int l  = t & 63;
  const int lr = l & 15;          /* fragment row/col index */
  const int g  = l >> 4;          /* k-slice group 0..3 */

  /* stage j-tile: pure linear copies, ZERO conversions */
  *(bf16x8*)(LB1 + t * 8) = *(const bf16x8*)(bP + (size_t)jt * 4096 + t * 8);
  if (t < TILE)
    *(bf16x8*)(LFB + t * 8) = *(const bf16x8*)(foh + (size_t)jt * 1024 + t * 8);

  /* A fragments: single 16B global loads */
  const int arow = it * TILE + w * 16 + lr;
  const bf16x8 afrag = *(const bf16x8*)(aP + (size_t)arow * 32 + g * 8);
  bf16x8 afrag3;
  if (g == 0) afrag3 = *(const bf16x8*)(foh + (size_t)arow * 8);
  else        { bf16x8 z = {0,0,0,0,0,0,0,0}; afrag3 = z; }

  __syncthreads();   /* LB1/LFB visible */

  /* hoist B and mask fragments into registers: loop has ZERO memory ops */
  bf16x8 b1f[8], m3[8];
#pragma unroll
  for (int mj = 0; mj < 8; ++mj)
    b1f[mj] = *(const bf16x8*)(LB1 + (mj * 16 + lr) * 32 + g * 8);
  if (g == 0) {
#pragma unroll
    for (int mj = 0; mj < 8; ++mj)
      m3[mj] = *(const bf16x8*)(LFB + (mj * 16 + lr) * 8);
  } else {
    bf16x8 z = {0,0,0,0,0,0,0,0};
#pragma unroll
    for (int mj = 0; mj < 8; ++mj) m3[mj] = z;
  }

  const f32x4 zf = {0.0f, 0.0f, 0.0f, 0.0f};
  float accT = 0.0f, accS = 0.0f;
#pragma unroll
  for (int mj = 0; mj < 8; ++mj) {
    /* acc == d2 (sq folded into K-slots); msk in {0,1} exact */
    const f32x4 acc = __builtin_amdgcn_mfma_f32_16x16x32_bf16(afrag,  b1f[mj], zf, 0, 0, 0);
    const f32x4 msk = __builtin_amdgcn_mfma_f32_16x16x32_bf16(afrag3, m3[mj],  zf, 0, 0, 0);
#pragma unroll
    for (int r = 0; r < 4; ++r) {
      const float dist = sqrt_abs(acc[r]);   /* |d2|: d2 >= -1e-4 only */
      accT += dist;
      accS = fmaf(msk[r], dist, accS);
    }
  }

  /* block reduction (fp32 partials ~1e5, fine) */
#pragma unroll
  for (int off = 32; off > 0; off >>= 1) {
    accT += __shfl_down(accT, off);
    accS += __shfl_down(accS, off);
  }
  if (l == 0) { rT[w] = accT; rS[w] = accS; }
  __syncthreads();
  if (t == 0) {
    float sT = 0.0f, sS = 0.0f;
#pragma unroll
    for (int k = 0; k < 8; ++k) { sT += rT[k]; sS += rS[k]; }
    const float wgt = (it == jt) ? 1.0f : 2.0f;
    const int bid = blockIdx.y * gridDim.x + blockIdx.x;
    pt[bid] = wgt * sT;
    ps[bid] = wgt * sS;
  }
}

__global__ __launch_bounds__(1024) void final_kernel(
    const float* __restrict__ pt, const float* __restrict__ ps,
    const int* __restrict__ idx, float* __restrict__ out) {
  const int t = threadIdx.x, w = t >> 6, l = t & 63;
  __shared__ float  HW[16][8];
  __shared__ double rTd[16], rSd[16];

  /* ballot histogram: 8 idx per thread via 2 coalesced int4 loads */
  const int4* p4 = (const int4*)idx;
  const int4 va = p4[t], vb = p4[t + 1024];
  int vals[8] = {va.x, va.y, va.z, va.w, vb.x, vb.y, vb.z, vb.w};
  float myCnt = 0.0f;            /* lane f (<6) counts family f */
#pragma unroll
  for (int rr = 0; rr < 8; ++rr) {
    const int f = FAM_LUT[vals[rr] & 63];
#pragma unroll
    for (int fam = 0; fam < 6; ++fam) {
      const unsigned long long mk = __ballot(f == fam);
      if (l == fam) myCnt += (float)__popcll(mk);
    }
  }
  if (l < 8) HW[w][l] = (l < 6) ? myCnt : 0.0f;

  double sT = 0.0, sS = 0.0;
  for (int k = t; k < NBLK; k += 1024) { sT += (double)pt[k]; sS += (double)ps[k]; }
#pragma unroll
  for (int off = 32; off > 0; off >>= 1) {
    sT += __shfl_down(sT, off);
    sS += __shfl_down(sS, off);
  }
  if (l == 0) { rTd[w] = sT; rSd[w] = sS; }
  __syncthreads();
  if (t == 0) {
    double tot = 0.0, sam = 0.0;
#pragma unroll
    for (int k = 0; k < 16; ++k) { tot += rTd[k]; sam += rSd[k]; }
    double same_sum = 0.0;
    for (int f = 0; f < 6; ++f) {
      double c = 0.0;
      for (int k = 0; k < 16; ++k) c += (double)HW[k][f];
      same_sum += c * c;
    }
    const double total  = (double)N_ROWS * (double)N_ROWS;
    const double same_d = sam / (same_sum + 1e-10);
    const double diff_d = (tot - sam) / (total - same_sum + 1e-10);
    double loss = same_d - 0.5 * diff_d + 1.0;
    out[0] = (float)(loss > 0.0 ? loss : 0.0);
  }
}

extern "C" void kernel_launch(void* const* d_in, const int* in_sizes, int n_in,
                              void* d_out, int out_size, void* d_ws, size_t ws_size,
                              hipStream_t stream) {
  const float* emb = (const float*)d_in[0];
  const int*   idx = (const int*)d_in[1];
  char* ws = (char*)d_ws;
  float*          pt  = (float*)(ws + OFF_PT);
  float*          ps  = (float*)(ws + OFF_PS);
  unsigned short* aP  = (unsigned short*)(ws + OFF_AP);
  unsigned short* bP  = (unsigned short*)(ws + OFF_BP);
  unsigned short* foh = (unsigned short*)(ws + OFF_FOH);

  prep_kernel<<<dim3(N_ROWS / 256), dim3(256), 0, stream>>>(emb, idx, aP, bP, foh);
  pair_kernel<<<dim3(NT + 1, NT / 2), dim3(512), 0, stream>>>(aP, bP, foh, pt, ps);
  final_kernel<<<dim3(1), dim3(1024), 0, stream>>>(pt, ps, idx, (float*)d_out);
}

// Round 14
// 21.931 us; speedup vs baseline: 1.1946x; 1.1946x over previous
//
#include <hip/hip_runtime.h>
#include <math.h>

#define N_ROWS 8192
#define D 16
#define TILE 128
#define NT 64            /* 8192/128 */
#define NPAIR 1056       /* sum over rows of ceil((NT-it)/2) */

/* workspace layout (bytes) */
#define OFF_PT   0            /* float pt[1056] */
#define OFF_PS   8192         /* float ps[1056] */

typedef short  bf16x8 __attribute__((ext_vector_type(8)));
typedef float  f32x4  __attribute__((ext_vector_type(4)));

#define BF_ONE ((unsigned short)0x3F80)

/* codon index -> biosynthetic family id (K resolves to aspartate; '*' -> -1)
   families: 0=glutamate 1=aspartate 2=serine 3=pyruvate 4=aromatic 5=histidine */
__device__ __constant__ signed char FAM_LUT[64] = {
  4,4,3,3, 3,3,3,3,   /* UUU..CUG: F F L L L L L L */
  1,1,1,1, 3,3,3,3,   /* AUU..GUG: I I I M V V V V */
  2,2,2,2, 0,0,0,0,   /* UCU..CCG: S S S S P P P P */
  1,1,1,1, 3,3,3,3,   /* ACU..GCG: T T T T A A A A */
  4,4,-1,-1, 5,5,0,0, /* UAU..CAG: Y Y * * H H Q Q */
  1,1,1,1, 1,1,0,0,   /* AAU..GAG: N N K K D D E E */
  2,2,-1,4, 0,0,0,0,  /* UGU..CGG: C C * W R R R R */
  2,2,0,0, 2,2,2,2    /* AGU..GGG: S S R R G G G G */
};

__device__ __forceinline__ unsigned short f2bf(float f) {   /* RNE, finite inputs */
  unsigned u = __float_as_uint(f);
  u += 0x7fffu + ((u >> 16) & 1u);
  return (unsigned short)(u >> 16);
}
__device__ __forceinline__ float bf2f(unsigned short s) {
  return __uint_as_float((unsigned)s << 16);
}
__device__ __forceinline__ float sqrt_abs(float x) {   /* abs is a free VOP3 mod */
  float r;
  asm("v_sqrt_f32 %0, abs(%1)" : "=v"(r) : "v"(x));
  return r;
}
/* S(m) = sum_{n=1..m} ceil(n/2) */
__device__ __forceinline__ int S_of(int m) {
  return (m & 1) ? (((m + 1) * (m + 1)) >> 2) : ((m * (m + 2)) >> 2);
}

/* Operand layout (K=32 slots); distances of the bf16-ROUNDED point set,
   sq computed FROM rounded coords (R12's math, bit-identical):
   A : [-2b_bf(0..15) | ONE, ONE, sqi_hi, sqi_lo, 0 x4 | 0 x8]
   B : [ b_bf(0..15)  | sqj_hi, sqj_lo, ONE, ONE, 0 x4 | 0 x8]
   => acc(A_i,B_j) = sqi + sqj - 2*dot = d2.  Mask via one-hot MFMA. */
__global__ __launch_bounds__(512, 4) void pair_kernel(
    const float* __restrict__ emb, const int* __restrict__ idx,
    float* __restrict__ pt, float* __restrict__ ps) {
  /* flat block -> (it, pair p): row it=NT-m owns tiles (it+2p, it+2p+1) */
  const int b = blockIdx.x;
  const int cc = NPAIR - b;                       /* in [1, NPAIR] */
  int m = (int)(2.0f * sqrtf((float)cc));
  if (m > NT) m = NT;
  if (m < 1) m = 1;
  while (S_of(m) < cc) ++m;
  while (m > 1 && S_of(m - 1) >= cc) --m;
  const int it  = NT - m;
  const int p   = b - (NPAIR - S_of(m));
  const int jt0 = it + 2 * p;
  const int jt1 = jt0 + 1;
  const bool v1 = (jt1 < NT);

  __shared__ __align__(16) unsigned short LB1[8192];  /* 16KB: 2 j-tiles [row][32] */
  __shared__ __align__(16) unsigned short LFB[2048];  /* 4KB: 2 j-tile one-hots */
  __shared__ __align__(16) unsigned short LFA[1024];  /* 2KB: i one-hot */
  __shared__ __align__(16) unsigned short LZ[8];      /* 16B zeros */
  __shared__ float SQIF[TILE];
  __shared__ float rT[8], rS[8];

  const int t  = threadIdx.x;
  const int w  = t >> 6;          /* wave 0..7: i-strip w */
  const int l  = t & 63;
  const int lr = l & 15;          /* fragment row/col index */
  const int g  = l >> 4;          /* k-slice group 0..3 */

  /* (a) j-side staging: t<256, one j-row each (tile = t>>7) */
  if (t < 256) {
    const int  jd    = t >> 7;                  /* which of the two tiles */
    const int  rl    = t & 127;
    const int  jtile = jd ? jt1 : jt0;
    const bool valid = (jtile < NT);
    const int  row   = min(jtile, NT - 1) * TILE + rl;
    const float4* s4 = (const float4*)(emb + (size_t)row * D);
    float4 a0 = s4[0], a1 = s4[1], a2 = s4[2], a3 = s4[3];
    float v[16];
    v[0]=a0.x; v[1]=a0.y; v[2]=a0.z; v[3]=a0.w;
    v[4]=a1.x; v[5]=a1.y; v[6]=a1.z; v[7]=a1.w;
    v[8]=a2.x; v[9]=a2.y; v[10]=a2.z; v[11]=a2.w;
    v[12]=a3.x; v[13]=a3.y; v[14]=a3.z; v[15]=a3.w;
    unsigned short bh[16];
#pragma unroll
    for (int k = 0; k < 16; ++k) bh[k] = valid ? f2bf(v[k]) : (unsigned short)0;
    float ss = bf2f(bh[0]) * bf2f(bh[0]);       /* sq of ROUNDED coords */
#pragma unroll
    for (int k = 1; k < 16; ++k) { const float rv = bf2f(bh[k]); ss = fmaf(rv, rv, ss); }
    const unsigned short sqh = f2bf(ss);
    const unsigned short sql = f2bf(ss - bf2f(sqh));
    unsigned short c2[8] = {sqh, sql, BF_ONE, BF_ONE, 0, 0, 0, 0};
    if (!valid) { c2[0] = 0; c2[1] = 0; c2[2] = 0; c2[3] = 0; }
    unsigned short cz[8] = {0, 0, 0, 0, 0, 0, 0, 0};
    unsigned short* d1 = LB1 + t * 32;
    *(bf16x8*)(d1 + 0)  = *(bf16x8*)&bh[0];
    *(bf16x8*)(d1 + 8)  = *(bf16x8*)&bh[8];
    *(bf16x8*)(d1 + 16) = *(bf16x8*)c2;
    *(bf16x8*)(d1 + 24) = *(bf16x8*)cz;
    const int f = valid ? FAM_LUT[idx[row] & 63] : -9;
    unsigned short oh[8];
#pragma unroll
    for (int k = 0; k < 8; ++k) oh[k] = (f == k) ? BF_ONE : (unsigned short)0;
    *(bf16x8*)(LFB + t * 8) = *(bf16x8*)oh;
  } else if (t < 384) {
    /* (b) i-side scalars: one i-row each */
    const int local = t - 256;
    const int row = it * TILE + local;
    const float4* s4 = (const float4*)(emb + (size_t)row * D);
    float4 a0 = s4[0], a1 = s4[1], a2 = s4[2], a3 = s4[3];
    float v[16];
    v[0]=a0.x; v[1]=a0.y; v[2]=a0.z; v[3]=a0.w;
    v[4]=a1.x; v[5]=a1.y; v[6]=a1.z; v[7]=a1.w;
    v[8]=a2.x; v[9]=a2.y; v[10]=a2.z; v[11]=a2.w;
    v[12]=a3.x; v[13]=a3.y; v[14]=a3.z; v[15]=a3.w;
    float ss = 0.0f;
#pragma unroll
    for (int k = 0; k < 16; ++k) { const float rv = bf2f(f2bf(v[k])); ss = fmaf(rv, rv, ss); }
    SQIF[local] = ss;
    const int f = FAM_LUT[idx[row] & 63];
    unsigned short oh[8];
#pragma unroll
    for (int k = 0; k < 8; ++k) oh[k] = (f == k) ? BF_ONE : (unsigned short)0;
    *(bf16x8*)(LFA + local * 8) = *(bf16x8*)oh;
  } else if (t == 384) {
    bf16x8 z = {0,0,0,0,0,0,0,0};
    *(bf16x8*)LZ = z;
  }

  /* A fragment part 1 (no LDS dep): -2*a_bf for g<2 */
  const int arow = it * TILE + w * 16 + lr;
  const float4* a4 = (const float4*)(emb + (size_t)arow * D + (g & 1) * 8);
  float4 c0 = a4[0], c1 = a4[1];
  float va[8];
  va[0]=c0.x; va[1]=c0.y; va[2]=c0.z; va[3]=c0.w;
  va[4]=c1.x; va[5]=c1.y; va[6]=c1.z; va[7]=c1.w;
  unsigned short f8[8];
#pragma unroll
  for (int k = 0; k < 8; ++k) f8[k] = f2bf(-2.0f * bf2f(f2bf(va[k])));

  __syncthreads();   /* LB1/LFB/LFA/SQIF/LZ visible */

  /* A fragment part 2: g==2 carries the sq-fold slots; g==3 zero */
  if (g >= 2) {
#pragma unroll
    for (int k = 0; k < 8; ++k) f8[k] = 0;
    if (g == 2) {
      const float sq = SQIF[w * 16 + lr];
      const unsigned short sqh = f2bf(sq);
      f8[0] = BF_ONE; f8[1] = BF_ONE;
      f8[2] = sqh;    f8[3] = f2bf(sq - bf2f(sqh));
    }
  }
  const bf16x8 afrag = *(bf16x8*)f8;
  bf16x8 afrag3;
  if (g == 0) afrag3 = *(const bf16x8*)(LFA + (w * 16 + lr) * 8);
  else        { bf16x8 z = {0,0,0,0,0,0,0,0}; afrag3 = z; }

  const unsigned short* p3 = (g == 0) ? (LFB + lr * 8) : LZ;
  const int step3 = (g == 0) ? 128 : 0;     /* ushorts per mj group */
  const int boff  = lr * 32 + g * 8;
  const f32x4 zf = {0.0f, 0.0f, 0.0f, 0.0f};
  float tT0 = 0.0f, tS0 = 0.0f, tT1 = 0.0f, tS1 = 0.0f;
#pragma unroll
  for (int mj = 0; mj < 16; ++mj) {
    const bf16x8 b1f = *(const bf16x8*)(LB1 + (mj * 16) * 32 + boff);
    const bf16x8 m3  = *(const bf16x8*)(p3 + mj * step3);
    /* acc == d2 (sq folded); msk in {0,1} exact */
    const f32x4 acc = __builtin_amdgcn_mfma_f32_16x16x32_bf16(afrag,  b1f, zf, 0, 0, 0);
    const f32x4 msk = __builtin_amdgcn_mfma_f32_16x16x32_bf16(afrag3, m3,  zf, 0, 0, 0);
#pragma unroll
    for (int r = 0; r < 4; ++r) {
      const float dist = sqrt_abs(acc[r]);   /* d2 >= -1e-4 only */
      if (mj < 8) { tT0 += dist; tS0 = fmaf(msk[r], dist, tS0); }
      else        { tT1 += dist; tS1 = fmaf(msk[r], dist, tS1); }
    }
  }

  /* per-tile weights, then block reduction */
  const float w0 = (jt0 == it) ? 1.0f : 2.0f;
  const float w1 = v1 ? 2.0f : 0.0f;
  float accT = fmaf(w0, tT0, w1 * tT1);
  float accS = fmaf(w0, tS0, w1 * tS1);
#pragma unroll
  for (int off = 32; off > 0; off >>= 1) {
    accT += __shfl_down(accT, off);
    accS += __shfl_down(accS, off);
  }
  if (l == 0) { rT[w] = accT; rS[w] = accS; }
  __syncthreads();
  if (t == 0) {
    float sT = 0.0f, sS = 0.0f;
#pragma unroll
    for (int k = 0; k < 8; ++k) { sT += rT[k]; sS += rS[k]; }
    pt[b] = sT;
    ps[b] = sS;
  }
}

__global__ __launch_bounds__(1024) void final_kernel(
    const float* __restrict__ pt, const float* __restrict__ ps,
    const int* __restrict__ idx, float* __restrict__ out) {
  const int t = threadIdx.x, w = t >> 6, l = t & 63;
  __shared__ float  HW[16][8];
  __shared__ double rTd[16], rSd[16];

  /* ballot histogram: 8 idx per thread via 2 coalesced int4 loads */
  const int4* p4 = (const int4*)idx;
  const int4 va = p4[t], vb = p4[t + 1024];
  int vals[8] = {va.x, va.y, va.z, va.w, vb.x, vb.y, vb.z, vb.w};
  float myCnt = 0.0f;            /* lane f (<6) counts family f */
#pragma unroll
  for (int rr = 0; rr < 8; ++rr) {
    const int f = FAM_LUT[vals[rr] & 63];
#pragma unroll
    for (int fam = 0; fam < 6; ++fam) {
      const unsigned long long mk = __ballot(f == fam);
      if (l == fam) myCnt += (float)__popcll(mk);
    }
  }
  if (l < 8) HW[w][l] = (l < 6) ? myCnt : 0.0f;

  double sT = 0.0, sS = 0.0;
  for (int k = t; k < NPAIR; k += 1024) { sT += (double)pt[k]; sS += (double)ps[k]; }
#pragma unroll
  for (int off = 32; off > 0; off >>= 1) {
    sT += __shfl_down(sT, off);
    sS += __shfl_down(sS, off);
  }
  if (l == 0) { rTd[w] = sT; rSd[w] = sS; }
  __syncthreads();
  if (t == 0) {
    double tot = 0.0, sam = 0.0;
#pragma unroll
    for (int k = 0; k < 16; ++k) { tot += rTd[k]; sam += rSd[k]; }
    double same_sum = 0.0;
    for (int f = 0; f < 6; ++f) {
      double c = 0.0;
      for (int k = 0; k < 16; ++k) c += (double)HW[k][f];
      same_sum += c * c;
    }
    const double total  = (double)N_ROWS * (double)N_ROWS;
    const double same_d = sam / (same_sum + 1e-10);
    const double diff_d = (tot - sam) / (total - same_sum + 1e-10);
    double loss = same_d - 0.5 * diff_d + 1.0;
    out[0] = (float)(loss > 0.0 ? loss : 0.0);
  }
}

extern "C" void kernel_launch(void* const* d_in, const int* in_sizes, int n_in,
                              void* d_out, int out_size, void* d_ws, size_t ws_size,
                              hipStream_t stream) {
  const float* emb = (const float*)d_in[0];
  const int*   idx = (const int*)d_in[1];
  char* ws = (char*)d_ws;
  float* pt = (float*)(ws + OFF_PT);
  float* ps = (float*)(ws + OFF_PS);

  pair_kernel<<<dim3(NPAIR), dim3(512), 0, stream>>>(emb, idx, pt, ps);
  final_kernel<<<dim3(1), dim3(1024), 0, stream>>>(pt, ps, idx, (float*)d_out);
}